// Round 5
// baseline (399.604 us; speedup 1.0000x reference)
//
#include <hip/hip_runtime.h>

// ===== DIAGNOSTIC ROUND: idempotent x2 work-repeat =====
// The real kernel (~147us) hides below the harness's ~170us poison-fills in
// rocprof top-5, so we have never seen its counters. This round repeats the
// identical tile computation twice (same threads -> same addresses -> same
// values; bit-identical output) purely to surface hyp_kernel as the top
// dispatch with full counters. Expected dur_us ~= 465 (sacrificial).

#define N_SEQ 2048
#define D_DIM 64
#define BH_CNT 16
#define TILE 64     // 64x64 output tile per block
#define LDSTR 72    // bf16 row stride in shorts (64 + 8 pad)
#define TSTR 68     // fp32 store-staging row stride in floats (64 + 4 pad)

typedef __attribute__((ext_vector_type(8))) short bf16x8;
typedef __attribute__((ext_vector_type(4))) float f32x4;

__device__ __forceinline__ short f2bf(float f) {
  union { float f; unsigned u; } v; v.f = f;
  unsigned r = v.u + 0x7FFFu + ((v.u >> 16) & 1u);
  return (short)(r >> 16);
}

__device__ __forceinline__ float hyp_dist(float qns, float kns, float qk) {
  float diff  = fmaxf(qns + kns - 2.0f * qk, 0.0f);
  float denom = fmaxf((1.0f - qns) * (1.0f - kns), 1e-6f);
  float t2 = __fdividef(2.0f * diff, denom);
  float s  = __builtin_amdgcn_sqrtf(t2 * (t2 + 2.0f));
  return __logf(1.0f + t2 + s);  // arccosh(1+t2)
}

__global__ void __launch_bounds__(256)
hyp_kernel(const float* __restrict__ qg,
           const float* __restrict__ kg,
           float* __restrict__ out)
{
  __shared__ __align__(16) char smem_raw[TILE * LDSTR * 2 * sizeof(short)];
  __shared__ float qn_s[TILE];
  __shared__ float kn_s[TILE];
  short* Qs = (short*)smem_raw;
  short* Ks = Qs + TILE * LDSTR;
  float* Ts = (float*)smem_raw;

  const int t  = threadIdx.x;
  const int bh = blockIdx.z;
  const int ti = blockIdx.y;  // Q row tile (i)
  const int tj = blockIdx.x;  // K row tile (j)

  const int row  = t >> 2;        // 0..63
  const int part = t & 3;         // 0..3
  const float* gq = qg + ((size_t)bh * N_SEQ + (size_t)ti * TILE) * D_DIM;
  const float* gk = kg + ((size_t)bh * N_SEQ + (size_t)tj * TILE) * D_DIM;

  const int lane = t & 63;
  const int wv   = t >> 6;          // 4 waves, 2x2 over the 64x64 tile
  const int wj   = (wv & 1) * 32;   // j sub-block (MFMA m axis)
  const int wi   = (wv >> 1) * 32;  // i sub-block (MFMA n axis)
  const int l15  = lane & 15;
  const int quad = lane >> 4;

  float* outb = out + (size_t)bh * N_SEQ * N_SEQ
                    + (size_t)(ti * TILE) * N_SEQ + tj * TILE;

  for (int rep = 0; rep < 2; ++rep) {
    if (rep) __syncthreads();  // prior rep's Ts reads done before re-staging

    // ---- stage Q/K 64x64 tiles (fp32 -> bf16), fused fp32 row norms ----
#pragma unroll
    for (int m = 0; m < 2; ++m) {
      const float* g = (m ? gk : gq) + row * D_DIM + part * 16;
      short* lds     = (m ? Ks : Qs) + row * LDSTR + part * 16;
      float* nrm     = m ? kn_s : qn_s;
      float4 v0 = ((const float4*)g)[0];
      float4 v1 = ((const float4*)g)[1];
      float4 v2 = ((const float4*)g)[2];
      float4 v3 = ((const float4*)g)[3];
      float p = v0.x*v0.x + v0.y*v0.y + v0.z*v0.z + v0.w*v0.w
              + v1.x*v1.x + v1.y*v1.y + v1.z*v1.z + v1.w*v1.w
              + v2.x*v2.x + v2.y*v2.y + v2.z*v2.z + v2.w*v2.w
              + v3.x*v3.x + v3.y*v3.y + v3.z*v3.z + v3.w*v3.w;
      p += __shfl_xor(p, 1);
      p += __shfl_xor(p, 2);
      if (part == 0) nrm[row] = p;
      bf16x8 pk0, pk1;
      pk0[0]=f2bf(v0.x); pk0[1]=f2bf(v0.y); pk0[2]=f2bf(v0.z); pk0[3]=f2bf(v0.w);
      pk0[4]=f2bf(v1.x); pk0[5]=f2bf(v1.y); pk0[6]=f2bf(v1.z); pk0[7]=f2bf(v1.w);
      pk1[0]=f2bf(v2.x); pk1[1]=f2bf(v2.y); pk1[2]=f2bf(v2.z); pk1[3]=f2bf(v2.w);
      pk1[4]=f2bf(v3.x); pk1[5]=f2bf(v3.y); pk1[6]=f2bf(v3.z); pk1[7]=f2bf(v3.w);
      ((bf16x8*)lds)[0] = pk0;
      ((bf16x8*)lds)[1] = pk1;
    }
    __syncthreads();

    // ---- MFMA: transposed product D[j][i] = sum_d K[j][d]*Q[i][d] ----
    const f32x4 zero = {0.0f, 0.0f, 0.0f, 0.0f};
    f32x4 acc[2][2];
#pragma unroll
    for (int a = 0; a < 2; ++a)
#pragma unroll
      for (int b = 0; b < 2; ++b)
        acc[a][b] = zero;

#pragma unroll
    for (int s = 0; s < 2; ++s) {       // K = 64 = 2 x 32
      const int koff = s * 32 + quad * 8;
      bf16x8 fa[2], fb[2];
#pragma unroll
      for (int mj = 0; mj < 2; ++mj)    // A operand: K rows (j)
        fa[mj] = *(const bf16x8*)&Ks[(wj + mj * 16 + l15) * LDSTR + koff];
#pragma unroll
      for (int ni = 0; ni < 2; ++ni)    // B operand: Q rows (i)
        fb[ni] = *(const bf16x8*)&Qs[(wi + ni * 16 + l15) * LDSTR + koff];
#pragma unroll
      for (int mj = 0; mj < 2; ++mj)
#pragma unroll
        for (int ni = 0; ni < 2; ++ni)
          acc[mj][ni] = __builtin_amdgcn_mfma_f32_16x16x32_bf16(
              fa[mj], fb[ni], acc[mj][ni], 0, 0, 0);
    }

    __syncthreads();  // LDS reads of Qs/Ks done -> reuse buffer as fp32 Ts

    // ---- epilogue: hyperbolic distance -> LDS staging tile ----
#pragma unroll
    for (int mj = 0; mj < 2; ++mj) {
      const int jl = wj + mj * 16 + quad * 4;     // 4 consecutive j per lane
      const float4 kn4 = *(const float4*)&kn_s[jl];
#pragma unroll
      for (int ni = 0; ni < 2; ++ni) {
        const int il = wi + ni * 16 + l15;
        const float qns = qn_s[il];
        f32x4 a4 = acc[mj][ni];
        f32x4 res;
        res[0] = hyp_dist(qns, kn4.x, a4[0]);
        res[1] = hyp_dist(qns, kn4.y, a4[1]);
        res[2] = hyp_dist(qns, kn4.z, a4[2]);
        res[3] = hyp_dist(qns, kn4.w, a4[3]);
        *(f32x4*)&Ts[il * TSTR + jl] = res;       // [i][j] tile, fp32
      }
    }
    __syncthreads();

    // ---- coalesced store: each 16-lane group writes a full 256B tile row ----
    const int l  = t & 15;           // 16B chunk within the 256B row
    const int rq = t >> 4;           // 16 row-groups across the block
#pragma unroll
    for (int p = 0; p < 4; ++p) {
      const int r = p * 16 + rq;     // tile row 0..63
      f32x4 v = *(const f32x4*)&Ts[r * TSTR + 4 * l];
      *(f32x4*)(outb + (size_t)r * N_SEQ + 4 * l) = v;
    }
  }
}

extern "C" void kernel_launch(void* const* d_in, const int* in_sizes, int n_in,
                              void* d_out, int out_size, void* d_ws, size_t ws_size,
                              hipStream_t stream) {
  const float* q = (const float*)d_in[0];
  const float* k = (const float*)d_in[1];
  float* out = (float*)d_out;
  dim3 grid(N_SEQ / TILE, N_SEQ / TILE, BH_CNT);  // (32,32,16) = 16384 blocks
  hyp_kernel<<<grid, 256, 0, stream>>>(q, k, out);
}

// Round 6
// 285.102 us; speedup vs baseline: 1.4016x; 1.4016x over previous
//
#include <hip/hip_runtime.h>

// Problem constants (B=2, H=8, N=2048, D=64, fp32 in, fp32 out)
#define N_SEQ 2048
#define D_DIM 64
#define BH_CNT 16
#define TILE 64     // 64x64 output tile per block
#define LDSTR 72    // bf16 row stride in shorts (64 + 8 pad)
#define TSTR 68     // fp32 store-staging row stride in floats (64 + 4 pad)

// Workspace layout (bytes):
//   [0)          q bf16: 2*8*2048*64 shorts = 4,194,304
//   [4,194,304)  k bf16:                      4,194,304
//   [8,388,608)  q row data: 32768 x float4 {2*qn, 1-qn, 1/(1-qn), 0} = 524,288
//   [8,912,896)  k row data: 32768 x float4                           = 524,288
//   total 9,437,184
#define WS_NEED 9437184ull
#define NROWS   32768    // 16 * 2048

typedef __attribute__((ext_vector_type(8))) short bf16x8;
typedef __attribute__((ext_vector_type(4))) float f32x4;

__device__ __forceinline__ short f2bf(float f) {
  union { float f; unsigned u; } v; v.f = f;
  unsigned r = v.u + 0x7FFFu + ((v.u >> 16) & 1u);
  return (short)(r >> 16);
}

// ===================== prep: fp32 -> bf16 + per-row terms =====================
__global__ void __launch_bounds__(256)
prep_kernel(const float* __restrict__ qg, const float* __restrict__ kg,
            short* __restrict__ qbf, short* __restrict__ kbf,
            float4* __restrict__ qrow, float4* __restrict__ krow)
{
  const int b = blockIdx.x;            // 2048 blocks: 1024 per tensor
  const int t = threadIdx.x;
  const int tensor = b >> 10;
  const float* src = tensor ? kg : qg;
  short* dbf       = tensor ? kbf : qbf;
  float4* drow     = tensor ? krow : qrow;

  const int r   = (b & 1023) * 32 + (t >> 3);  // global row 0..32767
  const int sub = t & 7;                        // 8 threads per 64-elem row
  const size_t e = (size_t)r * 64 + sub * 8;

  float4 v0 = ((const float4*)(src + e))[0];
  float4 v1 = ((const float4*)(src + e))[1];
  float p = v0.x*v0.x + v0.y*v0.y + v0.z*v0.z + v0.w*v0.w
          + v1.x*v1.x + v1.y*v1.y + v1.z*v1.z + v1.w*v1.w;
  p += __shfl_xor(p, 1);
  p += __shfl_xor(p, 2);
  p += __shfl_xor(p, 4);

  bf16x8 pk;
  pk[0]=f2bf(v0.x); pk[1]=f2bf(v0.y); pk[2]=f2bf(v0.z); pk[3]=f2bf(v0.w);
  pk[4]=f2bf(v1.x); pk[5]=f2bf(v1.y); pk[6]=f2bf(v1.z); pk[7]=f2bf(v1.w);
  *(bf16x8*)&dbf[e] = pk;

  if (sub == 0) {
    float a = 1.0f - p;
    drow[r] = make_float4(2.0f * p, a, 1.0f / a, 0.0f);
  }
}

// ===================== main: MFMA + cheap epilogue =====================
__global__ void __launch_bounds__(256)
hyp_main(const short* __restrict__ qbf, const short* __restrict__ kbf,
         const float4* __restrict__ qrow, const float4* __restrict__ krow,
         float* __restrict__ out)
{
  __shared__ __align__(16) char smem_raw[TILE * LDSTR * 2 * sizeof(short)];
  __shared__ __align__(16) float q2s[TILE], as_[TILE], ras[TILE];
  __shared__ __align__(16) float k2s[TILE], bs_[TILE], rbs[TILE];
  short* Qs = (short*)smem_raw;
  short* Ks = Qs + TILE * LDSTR;
  float* Ts = (float*)smem_raw;

  const int t  = threadIdx.x;
  const int bh = blockIdx.z;
  const int ti = blockIdx.y;
  const int tj = blockIdx.x;
  const int qrb = bh * N_SEQ + ti * TILE;   // global row base (row units)
  const int krb = bh * N_SEQ + tj * TILE;

  // ---- staging: pure bf16 copy into padded LDS (no conversion math) ----
  const int srow = t >> 3;          // 0..31
  const int scol = (t & 7) * 8;     // bf16 col
#pragma unroll
  for (int p = 0; p < 2; ++p) {
    const int r = srow + p * 32;
    *(bf16x8*)&Qs[r * LDSTR + scol] =
        *(const bf16x8*)&qbf[(size_t)(qrb + r) * 64 + scol];
    *(bf16x8*)&Ks[r * LDSTR + scol] =
        *(const bf16x8*)&kbf[(size_t)(krb + r) * 64 + scol];
  }
  if (t < 64) {
    float4 v = qrow[qrb + t];
    q2s[t] = v.x; as_[t] = v.y; ras[t] = v.z;
  } else if (t < 128) {
    const int u = t - 64;
    float4 v = krow[krb + u];
    k2s[u] = v.x; bs_[u] = v.y; rbs[u] = v.z;
  }
  __syncthreads();

  // ---- MFMA: D[j][i] = sum_d K[j][d]*Q[i][d] (identical to verified R2) ----
  const int lane = t & 63;
  const int wv   = t >> 6;
  const int wj   = (wv & 1) * 32;
  const int wi   = (wv >> 1) * 32;
  const int l15  = lane & 15;
  const int quad = lane >> 4;

  const f32x4 zero = {0.0f, 0.0f, 0.0f, 0.0f};
  f32x4 acc[2][2];
#pragma unroll
  for (int a = 0; a < 2; ++a)
#pragma unroll
    for (int b = 0; b < 2; ++b)
      acc[a][b] = zero;

#pragma unroll
  for (int s = 0; s < 2; ++s) {
    const int koff = s * 32 + quad * 8;
    bf16x8 fa[2], fb[2];
#pragma unroll
    for (int mj = 0; mj < 2; ++mj)
      fa[mj] = *(const bf16x8*)&Ks[(wj + mj * 16 + l15) * LDSTR + koff];
#pragma unroll
    for (int ni = 0; ni < 2; ++ni)
      fb[ni] = *(const bf16x8*)&Qs[(wi + ni * 16 + l15) * LDSTR + koff];
#pragma unroll
    for (int mj = 0; mj < 2; ++mj)
#pragma unroll
      for (int ni = 0; ni < 2; ++ni)
        acc[mj][ni] = __builtin_amdgcn_mfma_f32_16x16x32_bf16(
            fa[mj], fb[ni], acc[mj][ni], 0, 0, 0);
  }

  __syncthreads();  // Qs/Ks reads done -> reuse buffer as fp32 Ts

  // ---- epilogue: acosh via separable reciprocals (no per-elem divide) ----
  // n = 2*diff = 2qn + 2kn - 4*qk (clamped >= 0)
  // iv = 1/denom = (1/(1-qn))*(1/(1-kn)), clamp case -> constant 1e6
  // res = log2(x + sqrt(x^2-1)) * ln2,  x = 1 + n*iv
#pragma unroll
  for (int mj = 0; mj < 2; ++mj) {
    const int jl = wj + mj * 16 + quad * 4;
    const float4 k2v = *(const float4*)&k2s[jl];
    const float4 bv  = *(const float4*)&bs_[jl];
    const float4 rbv = *(const float4*)&rbs[jl];
    const float* k2p = (const float*)&k2v;
    const float* bp  = (const float*)&bv;
    const float* rbp = (const float*)&rbv;
#pragma unroll
    for (int ni = 0; ni < 2; ++ni) {
      const int il = wi + ni * 16 + l15;
      const float q2  = q2s[il];
      const float av  = as_[il];
      const float rav = ras[il];
      f32x4 a4 = acc[mj][ni];
      f32x4 res;
#pragma unroll
      for (int j = 0; j < 4; ++j) {
        float n    = fmaxf(fmaf(-4.0f, a4[j], q2 + k2p[j]), 0.0f);
        float prod = av * bp[j];
        float iv   = rav * rbp[j];
        iv = (prod > 1e-6f) ? iv : 1e6f;
        float x = fmaf(n, iv, 1.0f);
        float s = __builtin_amdgcn_sqrtf(fmaf(x, x, -1.0f));
        res[j] = __log2f(x + s) * 0.6931471805599453f;
      }
      *(f32x4*)&Ts[il * TSTR + jl] = res;
    }
  }
  __syncthreads();

  // ---- coalesced store: each 16-lane group writes a full 256B tile row ----
  float* outb = out + (size_t)bh * N_SEQ * N_SEQ
                    + (size_t)(ti * TILE) * N_SEQ + tj * TILE;
  const int l  = t & 15;
  const int rq = t >> 4;
#pragma unroll
  for (int p = 0; p < 4; ++p) {
    const int r = p * 16 + rq;
    f32x4 v = *(const f32x4*)&Ts[r * TSTR + 4 * l];
    *(f32x4*)(outb + (size_t)r * N_SEQ + 4 * l) = v;
  }
}

// ===================== fallback: verified R2 self-contained kernel =====================
__device__ __forceinline__ float hyp_dist_fb(float qns, float kns, float qk) {
  float diff  = fmaxf(qns + kns - 2.0f * qk, 0.0f);
  float denom = fmaxf((1.0f - qns) * (1.0f - kns), 1e-6f);
  float t2 = __fdividef(2.0f * diff, denom);
  float s  = __builtin_amdgcn_sqrtf(t2 * (t2 + 2.0f));
  return __logf(1.0f + t2 + s);
}

__global__ void __launch_bounds__(256)
hyp_fb(const float* __restrict__ qg, const float* __restrict__ kg,
       float* __restrict__ out)
{
  __shared__ __align__(16) char smem_raw[TILE * LDSTR * 2 * sizeof(short)];
  __shared__ float qn_s[TILE];
  __shared__ float kn_s[TILE];
  short* Qs = (short*)smem_raw;
  short* Ks = Qs + TILE * LDSTR;
  float* Ts = (float*)smem_raw;

  const int t  = threadIdx.x;
  const int bh = blockIdx.z;
  const int ti = blockIdx.y;
  const int tj = blockIdx.x;

  const int row  = t >> 2;
  const int part = t & 3;
  const float* gq = qg + ((size_t)bh * N_SEQ + (size_t)ti * TILE) * D_DIM;
  const float* gk = kg + ((size_t)bh * N_SEQ + (size_t)tj * TILE) * D_DIM;
#pragma unroll
  for (int m = 0; m < 2; ++m) {
    const float* g = (m ? gk : gq) + row * D_DIM + part * 16;
    short* lds     = (m ? Ks : Qs) + row * LDSTR + part * 16;
    float* nrm     = m ? kn_s : qn_s;
    float4 v0 = ((const float4*)g)[0];
    float4 v1 = ((const float4*)g)[1];
    float4 v2 = ((const float4*)g)[2];
    float4 v3 = ((const float4*)g)[3];
    float p = v0.x*v0.x + v0.y*v0.y + v0.z*v0.z + v0.w*v0.w
            + v1.x*v1.x + v1.y*v1.y + v1.z*v1.z + v1.w*v1.w
            + v2.x*v2.x + v2.y*v2.y + v2.z*v2.z + v2.w*v2.w
            + v3.x*v3.x + v3.y*v3.y + v3.z*v3.z + v3.w*v3.w;
    p += __shfl_xor(p, 1);
    p += __shfl_xor(p, 2);
    if (part == 0) nrm[row] = p;
    bf16x8 pk0, pk1;
    pk0[0]=f2bf(v0.x); pk0[1]=f2bf(v0.y); pk0[2]=f2bf(v0.z); pk0[3]=f2bf(v0.w);
    pk0[4]=f2bf(v1.x); pk0[5]=f2bf(v1.y); pk0[6]=f2bf(v1.z); pk0[7]=f2bf(v1.w);
    pk1[0]=f2bf(v2.x); pk1[1]=f2bf(v2.y); pk1[2]=f2bf(v2.z); pk1[3]=f2bf(v2.w);
    pk1[4]=f2bf(v3.x); pk1[5]=f2bf(v3.y); pk1[6]=f2bf(v3.z); pk1[7]=f2bf(v3.w);
    ((bf16x8*)lds)[0] = pk0;
    ((bf16x8*)lds)[1] = pk1;
  }
  __syncthreads();

  const int lane = t & 63;
  const int wv   = t >> 6;
  const int wj   = (wv & 1) * 32;
  const int wi   = (wv >> 1) * 32;
  const int l15  = lane & 15;
  const int quad = lane >> 4;

  const f32x4 zero = {0.0f, 0.0f, 0.0f, 0.0f};
  f32x4 acc[2][2];
#pragma unroll
  for (int a = 0; a < 2; ++a)
#pragma unroll
    for (int b = 0; b < 2; ++b)
      acc[a][b] = zero;

#pragma unroll
  for (int s = 0; s < 2; ++s) {
    const int koff = s * 32 + quad * 8;
    bf16x8 fa[2], fb[2];
#pragma unroll
    for (int mj = 0; mj < 2; ++mj)
      fa[mj] = *(const bf16x8*)&Ks[(wj + mj * 16 + l15) * LDSTR + koff];
#pragma unroll
    for (int ni = 0; ni < 2; ++ni)
      fb[ni] = *(const bf16x8*)&Qs[(wi + ni * 16 + l15) * LDSTR + koff];
#pragma unroll
    for (int mj = 0; mj < 2; ++mj)
#pragma unroll
      for (int ni = 0; ni < 2; ++ni)
        acc[mj][ni] = __builtin_amdgcn_mfma_f32_16x16x32_bf16(
            fa[mj], fb[ni], acc[mj][ni], 0, 0, 0);
  }

  __syncthreads();

#pragma unroll
  for (int mj = 0; mj < 2; ++mj) {
    const int jl = wj + mj * 16 + quad * 4;
    const float4 kn4 = *(const float4*)&kn_s[jl];
#pragma unroll
    for (int ni = 0; ni < 2; ++ni) {
      const int il = wi + ni * 16 + l15;
      const float qns = qn_s[il];
      f32x4 a4 = acc[mj][ni];
      f32x4 res;
      res[0] = hyp_dist_fb(qns, kn4.x, a4[0]);
      res[1] = hyp_dist_fb(qns, kn4.y, a4[1]);
      res[2] = hyp_dist_fb(qns, kn4.z, a4[2]);
      res[3] = hyp_dist_fb(qns, kn4.w, a4[3]);
      *(f32x4*)&Ts[il * TSTR + jl] = res;
    }
  }
  __syncthreads();

  float* outb = out + (size_t)bh * N_SEQ * N_SEQ
                    + (size_t)(ti * TILE) * N_SEQ + tj * TILE;
  const int l  = t & 15;
  const int rq = t >> 4;
#pragma unroll
  for (int p = 0; p < 4; ++p) {
    const int r = p * 16 + rq;
    f32x4 v = *(const f32x4*)&Ts[r * TSTR + 4 * l];
    *(f32x4*)(outb + (size_t)r * N_SEQ + 4 * l) = v;
  }
}

extern "C" void kernel_launch(void* const* d_in, const int* in_sizes, int n_in,
                              void* d_out, int out_size, void* d_ws, size_t ws_size,
                              hipStream_t stream) {
  const float* q = (const float*)d_in[0];
  const float* k = (const float*)d_in[1];
  float* out = (float*)d_out;
  dim3 grid(N_SEQ / TILE, N_SEQ / TILE, BH_CNT);  // (32,32,16)

  if (ws_size >= WS_NEED && d_ws != nullptr) {
    short* qbf  = (short*)d_ws;
    short* kbf  = qbf + 2097152;
    float4* qrow = (float4*)((char*)d_ws + 8388608);
    float4* krow = qrow + NROWS;
    prep_kernel<<<dim3(2048, 1, 1), 256, 0, stream>>>(q, k, qbf, kbf, qrow, krow);
    hyp_main<<<grid, 256, 0, stream>>>(qbf, kbf, qrow, krow, out);
  } else {
    hyp_fb<<<grid, 256, 0, stream>>>(q, k, out);
  }
}

// Round 7
// 281.171 us; speedup vs baseline: 1.4212x; 1.0140x over previous
//
#include <hip/hip_runtime.h>

// Problem constants (B=2, H=8, N=2048, D=64, fp32 in, fp32 out)
#define N_SEQ 2048
#define D_DIM 64
#define BH_CNT 16
#define TILE 64     // 64x64 output tile per block
#define LDSTR 72    // bf16 row stride in shorts (64 + 8 pad)
#define TSTR 68     // fp32 store-staging row stride in floats (64 + 4 pad)

// Workspace layout (bytes):
//   [0)          q bf16: 2*8*2048*64 shorts = 4,194,304
//   [4,194,304)  k bf16:                      4,194,304
//   [8,388,608)  q row data: 32768 x float4 {2*qn, 1-qn, 1/(1-qn), 0} = 524,288
//   [8,912,896)  k row data: 32768 x float4                           = 524,288
//   total 9,437,184
#define WS_NEED 9437184ull
#define NROWS   32768    // 16 * 2048

typedef __attribute__((ext_vector_type(8))) short bf16x8;
typedef __attribute__((ext_vector_type(4))) float f32x4;

__device__ __forceinline__ short f2bf(float f) {
  union { float f; unsigned u; } v; v.f = f;
  unsigned r = v.u + 0x7FFFu + ((v.u >> 16) & 1u);
  return (short)(r >> 16);
}

// ===================== prep: fp32 -> bf16 + per-row terms =====================
__global__ void __launch_bounds__(256)
prep_kernel(const float* __restrict__ qg, const float* __restrict__ kg,
            short* __restrict__ qbf, short* __restrict__ kbf,
            float4* __restrict__ qrow, float4* __restrict__ krow)
{
  const int b = blockIdx.x;            // 2048 blocks: 1024 per tensor
  const int t = threadIdx.x;
  const int tensor = b >> 10;
  const float* src = tensor ? kg : qg;
  short* dbf       = tensor ? kbf : qbf;
  float4* drow     = tensor ? krow : qrow;

  const int r   = (b & 1023) * 32 + (t >> 3);  // global row 0..32767
  const int sub = t & 7;                        // 8 threads per 64-elem row
  const size_t e = (size_t)r * 64 + sub * 8;

  float4 v0 = ((const float4*)(src + e))[0];
  float4 v1 = ((const float4*)(src + e))[1];
  float p = v0.x*v0.x + v0.y*v0.y + v0.z*v0.z + v0.w*v0.w
          + v1.x*v1.x + v1.y*v1.y + v1.z*v1.z + v1.w*v1.w;
  p += __shfl_xor(p, 1);
  p += __shfl_xor(p, 2);
  p += __shfl_xor(p, 4);

  bf16x8 pk;
  pk[0]=f2bf(v0.x); pk[1]=f2bf(v0.y); pk[2]=f2bf(v0.z); pk[3]=f2bf(v0.w);
  pk[4]=f2bf(v1.x); pk[5]=f2bf(v1.y); pk[6]=f2bf(v1.z); pk[7]=f2bf(v1.w);
  *(bf16x8*)&dbf[e] = pk;

  if (sub == 0) {
    float a = 1.0f - p;
    drow[r] = make_float4(2.0f * p, a, 1.0f / a, 0.0f);
  }
}

// ===================== main: MFMA + cheap epilogue + XCD write-grouping =====================
__global__ void __launch_bounds__(256)
hyp_main(const short* __restrict__ qbf, const short* __restrict__ kbf,
         const float4* __restrict__ qrow, const float4* __restrict__ krow,
         float* __restrict__ out)
{
  __shared__ __align__(16) char smem_raw[TILE * LDSTR * 2 * sizeof(short)];
  __shared__ __align__(16) float q2s[TILE], as_[TILE], ras[TILE];
  __shared__ __align__(16) float k2s[TILE], bs_[TILE], rbs[TILE];
  short* Qs = (short*)smem_raw;
  short* Ks = Qs + TILE * LDSTR;
  float* Ts = (float*)smem_raw;

  const int t = threadIdx.x;

  // ---- XCD-aware swizzle for WRITE-stream locality ----
  // HW round-robins block h -> XCD h%8. Decode so all 32 tj tiles of one
  // (bh,ti) row-group land on the SAME XCD: that L2 fills a contiguous
  // 512KB output slab -> clustered eviction streams instead of scattered
  // 256B slices. Bijective for 16384 blocks (16384 % 8 == 0).
  const unsigned h = blockIdx.x;
  const int xcd = h & 7;
  const int tj  = (h >> 3) & 31;            // K col tile (j)
  const int rg  = (int)(h >> 8) * 8 + xcd;  // row-group 0..511
  const int bh  = rg >> 5;                  // 0..15
  const int ti  = rg & 31;                  // Q row tile (i)

  const int qrb = bh * N_SEQ + ti * TILE;   // global row base (row units)
  const int krb = bh * N_SEQ + tj * TILE;

  // ---- staging: pure bf16 copy into padded LDS (no conversion math) ----
  const int srow = t >> 3;          // 0..31
  const int scol = (t & 7) * 8;     // bf16 col
#pragma unroll
  for (int p = 0; p < 2; ++p) {
    const int r = srow + p * 32;
    *(bf16x8*)&Qs[r * LDSTR + scol] =
        *(const bf16x8*)&qbf[(size_t)(qrb + r) * 64 + scol];
    *(bf16x8*)&Ks[r * LDSTR + scol] =
        *(const bf16x8*)&kbf[(size_t)(krb + r) * 64 + scol];
  }
  if (t < 64) {
    float4 v = qrow[qrb + t];
    q2s[t] = v.x; as_[t] = v.y; ras[t] = v.z;
  } else if (t < 128) {
    const int u = t - 64;
    float4 v = krow[krb + u];
    k2s[u] = v.x; bs_[u] = v.y; rbs[u] = v.z;
  }
  __syncthreads();

  // ---- MFMA: D[j][i] = sum_d K[j][d]*Q[i][d] ----
  const int lane = t & 63;
  const int wv   = t >> 6;
  const int wj   = (wv & 1) * 32;
  const int wi   = (wv >> 1) * 32;
  const int l15  = lane & 15;
  const int quad = lane >> 4;

  const f32x4 zero = {0.0f, 0.0f, 0.0f, 0.0f};
  f32x4 acc[2][2];
#pragma unroll
  for (int a = 0; a < 2; ++a)
#pragma unroll
    for (int b = 0; b < 2; ++b)
      acc[a][b] = zero;

#pragma unroll
  for (int s = 0; s < 2; ++s) {
    const int koff = s * 32 + quad * 8;
    bf16x8 fa[2], fb[2];
#pragma unroll
    for (int mj = 0; mj < 2; ++mj)
      fa[mj] = *(const bf16x8*)&Ks[(wj + mj * 16 + l15) * LDSTR + koff];
#pragma unroll
    for (int ni = 0; ni < 2; ++ni)
      fb[ni] = *(const bf16x8*)&Qs[(wi + ni * 16 + l15) * LDSTR + koff];
#pragma unroll
    for (int mj = 0; mj < 2; ++mj)
#pragma unroll
      for (int ni = 0; ni < 2; ++ni)
        acc[mj][ni] = __builtin_amdgcn_mfma_f32_16x16x32_bf16(
            fa[mj], fb[ni], acc[mj][ni], 0, 0, 0);
  }

  __syncthreads();  // Qs/Ks reads done -> reuse buffer as fp32 Ts

  // ---- epilogue: acosh via separable reciprocals (no per-elem divide) ----
#pragma unroll
  for (int mj = 0; mj < 2; ++mj) {
    const int jl = wj + mj * 16 + quad * 4;
    const float4 k2v = *(const float4*)&k2s[jl];
    const float4 bv  = *(const float4*)&bs_[jl];
    const float4 rbv = *(const float4*)&rbs[jl];
    const float* k2p = (const float*)&k2v;
    const float* bp  = (const float*)&bv;
    const float* rbp = (const float*)&rbv;
#pragma unroll
    for (int ni = 0; ni < 2; ++ni) {
      const int il = wi + ni * 16 + l15;
      const float q2  = q2s[il];
      const float av  = as_[il];
      const float rav = ras[il];
      f32x4 a4 = acc[mj][ni];
      f32x4 res;
#pragma unroll
      for (int j = 0; j < 4; ++j) {
        float n    = fmaxf(fmaf(-4.0f, a4[j], q2 + k2p[j]), 0.0f);
        float prod = av * bp[j];
        float iv   = rav * rbp[j];
        iv = (prod > 1e-6f) ? iv : 1e6f;
        float x = fmaf(n, iv, 1.0f);
        float s = __builtin_amdgcn_sqrtf(fmaf(x, x, -1.0f));
        res[j] = __log2f(x + s) * 0.6931471805599453f;
      }
      *(f32x4*)&Ts[il * TSTR + jl] = res;
    }
  }
  __syncthreads();

  // ---- coalesced store: each 16-lane group writes a full 256B tile row ----
  float* outb = out + (size_t)bh * N_SEQ * N_SEQ
                    + (size_t)(ti * TILE) * N_SEQ + tj * TILE;
  const int l  = t & 15;
  const int rq = t >> 4;
#pragma unroll
  for (int p = 0; p < 4; ++p) {
    const int r = p * 16 + rq;
    f32x4 v = *(const f32x4*)&Ts[r * TSTR + 4 * l];
    *(f32x4*)(outb + (size_t)r * N_SEQ + 4 * l) = v;
  }
}

// ===================== fallback: verified R2 self-contained kernel =====================
__device__ __forceinline__ float hyp_dist_fb(float qns, float kns, float qk) {
  float diff  = fmaxf(qns + kns - 2.0f * qk, 0.0f);
  float denom = fmaxf((1.0f - qns) * (1.0f - kns), 1e-6f);
  float t2 = __fdividef(2.0f * diff, denom);
  float s  = __builtin_amdgcn_sqrtf(t2 * (t2 + 2.0f));
  return __logf(1.0f + t2 + s);
}

__global__ void __launch_bounds__(256)
hyp_fb(const float* __restrict__ qg, const float* __restrict__ kg,
       float* __restrict__ out)
{
  __shared__ __align__(16) char smem_raw[TILE * LDSTR * 2 * sizeof(short)];
  __shared__ float qn_s[TILE];
  __shared__ float kn_s[TILE];
  short* Qs = (short*)smem_raw;
  short* Ks = Qs + TILE * LDSTR;
  float* Ts = (float*)smem_raw;

  const int t  = threadIdx.x;
  const int bh = blockIdx.z;
  const int ti = blockIdx.y;
  const int tj = blockIdx.x;

  const int row  = t >> 2;
  const int part = t & 3;
  const float* gq = qg + ((size_t)bh * N_SEQ + (size_t)ti * TILE) * D_DIM;
  const float* gk = kg + ((size_t)bh * N_SEQ + (size_t)tj * TILE) * D_DIM;
#pragma unroll
  for (int m = 0; m < 2; ++m) {
    const float* g = (m ? gk : gq) + row * D_DIM + part * 16;
    short* lds     = (m ? Ks : Qs) + row * LDSTR + part * 16;
    float* nrm     = m ? kn_s : qn_s;
    float4 v0 = ((const float4*)g)[0];
    float4 v1 = ((const float4*)g)[1];
    float4 v2 = ((const float4*)g)[2];
    float4 v3 = ((const float4*)g)[3];
    float p = v0.x*v0.x + v0.y*v0.y + v0.z*v0.z + v0.w*v0.w
            + v1.x*v1.x + v1.y*v1.y + v1.z*v1.z + v1.w*v1.w
            + v2.x*v2.x + v2.y*v2.y + v2.z*v2.z + v2.w*v2.w
            + v3.x*v3.x + v3.y*v3.y + v3.z*v3.z + v3.w*v3.w;
    p += __shfl_xor(p, 1);
    p += __shfl_xor(p, 2);
    if (part == 0) nrm[row] = p;
    bf16x8 pk0, pk1;
    pk0[0]=f2bf(v0.x); pk0[1]=f2bf(v0.y); pk0[2]=f2bf(v0.z); pk0[3]=f2bf(v0.w);
    pk0[4]=f2bf(v1.x); pk0[5]=f2bf(v1.y); pk0[6]=f2bf(v1.z); pk0[7]=f2bf(v1.w);
    pk1[0]=f2bf(v2.x); pk1[1]=f2bf(v2.y); pk1[2]=f2bf(v2.z); pk1[3]=f2bf(v2.w);
    pk1[4]=f2bf(v3.x); pk1[5]=f2bf(v3.y); pk1[6]=f2bf(v3.z); pk1[7]=f2bf(v3.w);
    ((bf16x8*)lds)[0] = pk0;
    ((bf16x8*)lds)[1] = pk1;
  }
  __syncthreads();

  const int lane = t & 63;
  const int wv   = t >> 6;
  const int wj   = (wv & 1) * 32;
  const int wi   = (wv >> 1) * 32;
  const int l15  = lane & 15;
  const int quad = lane >> 4;

  const f32x4 zero = {0.0f, 0.0f, 0.0f, 0.0f};
  f32x4 acc[2][2];
#pragma unroll
  for (int a = 0; a < 2; ++a)
#pragma unroll
    for (int b = 0; b < 2; ++b)
      acc[a][b] = zero;

#pragma unroll
  for (int s = 0; s < 2; ++s) {
    const int koff = s * 32 + quad * 8;
    bf16x8 fa[2], fb[2];
#pragma unroll
    for (int mj = 0; mj < 2; ++mj)
      fa[mj] = *(const bf16x8*)&Ks[(wj + mj * 16 + l15) * LDSTR + koff];
#pragma unroll
    for (int ni = 0; ni < 2; ++ni)
      fb[ni] = *(const bf16x8*)&Qs[(wi + ni * 16 + l15) * LDSTR + koff];
#pragma unroll
    for (int mj = 0; mj < 2; ++mj)
#pragma unroll
      for (int ni = 0; ni < 2; ++ni)
        acc[mj][ni] = __builtin_amdgcn_mfma_f32_16x16x32_bf16(
            fa[mj], fb[ni], acc[mj][ni], 0, 0, 0);
  }

  __syncthreads();

#pragma unroll
  for (int mj = 0; mj < 2; ++mj) {
    const int jl = wj + mj * 16 + quad * 4;
    const float4 kn4 = *(const float4*)&kn_s[jl];
#pragma unroll
    for (int ni = 0; ni < 2; ++ni) {
      const int il = wi + ni * 16 + l15;
      const float qns = qn_s[il];
      f32x4 a4 = acc[mj][ni];
      f32x4 res;
      res[0] = hyp_dist_fb(qns, kn4.x, a4[0]);
      res[1] = hyp_dist_fb(qns, kn4.y, a4[1]);
      res[2] = hyp_dist_fb(qns, kn4.z, a4[2]);
      res[3] = hyp_dist_fb(qns, kn4.w, a4[3]);
      *(f32x4*)&Ts[il * TSTR + jl] = res;
    }
  }
  __syncthreads();

  float* outb = out + (size_t)bh * N_SEQ * N_SEQ
                    + (size_t)(ti * TILE) * N_SEQ + tj * TILE;
  const int l  = t & 15;
  const int rq = t >> 4;
#pragma unroll
  for (int p = 0; p < 4; ++p) {
    const int r = p * 16 + rq;
    f32x4 v = *(const f32x4*)&Ts[r * TSTR + 4 * l];
    *(f32x4*)(outb + (size_t)r * N_SEQ + 4 * l) = v;
  }
}

extern "C" void kernel_launch(void* const* d_in, const int* in_sizes, int n_in,
                              void* d_out, int out_size, void* d_ws, size_t ws_size,
                              hipStream_t stream) {
  const float* q = (const float*)d_in[0];
  const float* k = (const float*)d_in[1];
  float* out = (float*)d_out;

  if (ws_size >= WS_NEED && d_ws != nullptr) {
    short* qbf  = (short*)d_ws;
    short* kbf  = qbf + 2097152;
    float4* qrow = (float4*)((char*)d_ws + 8388608);
    float4* krow = qrow + NROWS;
    prep_kernel<<<dim3(2048, 1, 1), 256, 0, stream>>>(q, k, qbf, kbf, qrow, krow);
    hyp_main<<<dim3(16384, 1, 1), 256, 0, stream>>>(qbf, kbf, qrow, krow, out);
  } else {
    dim3 grid(N_SEQ / TILE, N_SEQ / TILE, BH_CNT);  // (32,32,16)
    hyp_fb<<<grid, 256, 0, stream>>>(q, k, out);
  }
}

// Round 8
// 272.791 us; speedup vs baseline: 1.4649x; 1.0307x over previous
//
#include <hip/hip_runtime.h>

// Problem constants (B=2, H=8, N=2048, D=64, fp32 in, fp32 out)
#define N_SEQ 2048
#define D_DIM 64
#define BH_CNT 16
#define TILE 64     // 64x64 output tile per block
#define LDSTR 72    // bf16 row stride in shorts (64 + 8 pad)
#define TSTR 68     // fp32 store-staging row stride in floats (64 + 4 pad)

// Workspace layout (bytes):
//   [0)          q bf16: 2*8*2048*64 shorts = 4,194,304
//   [4,194,304)  k bf16:                      4,194,304
//   [8,388,608)  q row data: 32768 x float4 {2*qn, 1-qn, 1/(1-qn), 0} = 524,288
//   [8,912,896)  k row data: 32768 x float4                           = 524,288
//   total 9,437,184
#define WS_NEED 9437184ull
#define NROWS   32768    // 16 * 2048

typedef __attribute__((ext_vector_type(8))) short bf16x8;
typedef __attribute__((ext_vector_type(4))) float f32x4;

__device__ __forceinline__ short f2bf(float f) {
  union { float f; unsigned u; } v; v.f = f;
  unsigned r = v.u + 0x7FFFu + ((v.u >> 16) & 1u);
  return (short)(r >> 16);
}

// ===================== prep: fp32 -> bf16 + per-row terms =====================
__global__ void __launch_bounds__(256)
prep_kernel(const float* __restrict__ qg, const float* __restrict__ kg,
            short* __restrict__ qbf, short* __restrict__ kbf,
            float4* __restrict__ qrow, float4* __restrict__ krow)
{
  const int b = blockIdx.x;            // 2048 blocks: 1024 per tensor
  const int t = threadIdx.x;
  const int tensor = b >> 10;
  const float* src = tensor ? kg : qg;
  short* dbf       = tensor ? kbf : qbf;
  float4* drow     = tensor ? krow : qrow;

  const int r   = (b & 1023) * 32 + (t >> 3);  // global row 0..32767
  const int sub = t & 7;                        // 8 threads per 64-elem row
  const size_t e = (size_t)r * 64 + sub * 8;

  float4 v0 = ((const float4*)(src + e))[0];
  float4 v1 = ((const float4*)(src + e))[1];
  float p = v0.x*v0.x + v0.y*v0.y + v0.z*v0.z + v0.w*v0.w
          + v1.x*v1.x + v1.y*v1.y + v1.z*v1.z + v1.w*v1.w;
  p += __shfl_xor(p, 1);
  p += __shfl_xor(p, 2);
  p += __shfl_xor(p, 4);

  bf16x8 pk;
  pk[0]=f2bf(v0.x); pk[1]=f2bf(v0.y); pk[2]=f2bf(v0.z); pk[3]=f2bf(v0.w);
  pk[4]=f2bf(v1.x); pk[5]=f2bf(v1.y); pk[6]=f2bf(v1.z); pk[7]=f2bf(v1.w);
  *(bf16x8*)&dbf[e] = pk;

  if (sub == 0) {
    float a = 1.0f - p;
    drow[r] = make_float4(2.0f * p, a, 1.0f / a, 0.0f);
  }
}

// ===================== main: MFMA + cheap epilogue + XCD grouping + nt stores =====================
__global__ void __launch_bounds__(256)
hyp_main(const short* __restrict__ qbf, const short* __restrict__ kbf,
         const float4* __restrict__ qrow, const float4* __restrict__ krow,
         float* __restrict__ out)
{
  __shared__ __align__(16) char smem_raw[TILE * LDSTR * 2 * sizeof(short)];
  __shared__ __align__(16) float q2s[TILE], as_[TILE], ras[TILE];
  __shared__ __align__(16) float k2s[TILE], bs_[TILE], rbs[TILE];
  short* Qs = (short*)smem_raw;
  short* Ks = Qs + TILE * LDSTR;
  float* Ts = (float*)smem_raw;

  const int t = threadIdx.x;

  // ---- XCD-aware swizzle for WRITE-stream locality (kept from R7) ----
  const unsigned h = blockIdx.x;
  const int xcd = h & 7;
  const int tj  = (h >> 3) & 31;            // K col tile (j)
  const int rg  = (int)(h >> 8) * 8 + xcd;  // row-group 0..511
  const int bh  = rg >> 5;                  // 0..15
  const int ti  = rg & 31;                  // Q row tile (i)

  const int qrb = bh * N_SEQ + ti * TILE;   // global row base (row units)
  const int krb = bh * N_SEQ + tj * TILE;

  // ---- staging: pure bf16 copy into padded LDS (no conversion math) ----
  const int srow = t >> 3;          // 0..31
  const int scol = (t & 7) * 8;     // bf16 col
#pragma unroll
  for (int p = 0; p < 2; ++p) {
    const int r = srow + p * 32;
    *(bf16x8*)&Qs[r * LDSTR + scol] =
        *(const bf16x8*)&qbf[(size_t)(qrb + r) * 64 + scol];
    *(bf16x8*)&Ks[r * LDSTR + scol] =
        *(const bf16x8*)&kbf[(size_t)(krb + r) * 64 + scol];
  }
  if (t < 64) {
    float4 v = qrow[qrb + t];
    q2s[t] = v.x; as_[t] = v.y; ras[t] = v.z;
  } else if (t < 128) {
    const int u = t - 64;
    float4 v = krow[krb + u];
    k2s[u] = v.x; bs_[u] = v.y; rbs[u] = v.z;
  }
  __syncthreads();

  // ---- MFMA: D[j][i] = sum_d K[j][d]*Q[i][d] ----
  const int lane = t & 63;
  const int wv   = t >> 6;
  const int wj   = (wv & 1) * 32;
  const int wi   = (wv >> 1) * 32;
  const int l15  = lane & 15;
  const int quad = lane >> 4;

  const f32x4 zero = {0.0f, 0.0f, 0.0f, 0.0f};
  f32x4 acc[2][2];
#pragma unroll
  for (int a = 0; a < 2; ++a)
#pragma unroll
    for (int b = 0; b < 2; ++b)
      acc[a][b] = zero;

#pragma unroll
  for (int s = 0; s < 2; ++s) {
    const int koff = s * 32 + quad * 8;
    bf16x8 fa[2], fb[2];
#pragma unroll
    for (int mj = 0; mj < 2; ++mj)
      fa[mj] = *(const bf16x8*)&Ks[(wj + mj * 16 + l15) * LDSTR + koff];
#pragma unroll
    for (int ni = 0; ni < 2; ++ni)
      fb[ni] = *(const bf16x8*)&Qs[(wi + ni * 16 + l15) * LDSTR + koff];
#pragma unroll
    for (int mj = 0; mj < 2; ++mj)
#pragma unroll
      for (int ni = 0; ni < 2; ++ni)
        acc[mj][ni] = __builtin_amdgcn_mfma_f32_16x16x32_bf16(
            fa[mj], fb[ni], acc[mj][ni], 0, 0, 0);
  }

  __syncthreads();  // Qs/Ks reads done -> reuse buffer as fp32 Ts

  // ---- epilogue: acosh via separable reciprocals (no per-elem divide) ----
#pragma unroll
  for (int mj = 0; mj < 2; ++mj) {
    const int jl = wj + mj * 16 + quad * 4;
    const float4 k2v = *(const float4*)&k2s[jl];
    const float4 bv  = *(const float4*)&bs_[jl];
    const float4 rbv = *(const float4*)&rbs[jl];
    const float* k2p = (const float*)&k2v;
    const float* bp  = (const float*)&bv;
    const float* rbp = (const float*)&rbv;
#pragma unroll
    for (int ni = 0; ni < 2; ++ni) {
      const int il = wi + ni * 16 + l15;
      const float q2  = q2s[il];
      const float av  = as_[il];
      const float rav = ras[il];
      f32x4 a4 = acc[mj][ni];
      f32x4 res;
#pragma unroll
      for (int j = 0; j < 4; ++j) {
        float n    = fmaxf(fmaf(-4.0f, a4[j], q2 + k2p[j]), 0.0f);
        float prod = av * bp[j];
        float iv   = rav * rbp[j];
        iv = (prod > 1e-6f) ? iv : 1e6f;
        float x = fmaf(n, iv, 1.0f);
        float s = __builtin_amdgcn_sqrtf(fmaf(x, x, -1.0f));
        res[j] = __log2f(x + s) * 0.6931471805599453f;
      }
      *(f32x4*)&Ts[il * TSTR + jl] = res;
    }
  }
  __syncthreads();

  // ---- coalesced NON-TEMPORAL store: 256B runs, streaming eviction ----
  // Output lines are write-once/never-read: nt policy -> prompt in-order
  // L2 eviction (clustered HBM write stream) + no L2 thrash of the ws.
  float* outb = out + (size_t)bh * N_SEQ * N_SEQ
                    + (size_t)(ti * TILE) * N_SEQ + tj * TILE;
  const int l  = t & 15;
  const int rq = t >> 4;
#pragma unroll
  for (int p = 0; p < 4; ++p) {
    const int r = p * 16 + rq;
    f32x4 v = *(const f32x4*)&Ts[r * TSTR + 4 * l];
    __builtin_nontemporal_store(v, (f32x4*)(outb + (size_t)r * N_SEQ + 4 * l));
  }
}

// ===================== fallback: verified R2 self-contained kernel =====================
__device__ __forceinline__ float hyp_dist_fb(float qns, float kns, float qk) {
  float diff  = fmaxf(qns + kns - 2.0f * qk, 0.0f);
  float denom = fmaxf((1.0f - qns) * (1.0f - kns), 1e-6f);
  float t2 = __fdividef(2.0f * diff, denom);
  float s  = __builtin_amdgcn_sqrtf(t2 * (t2 + 2.0f));
  return __logf(1.0f + t2 + s);
}

__global__ void __launch_bounds__(256)
hyp_fb(const float* __restrict__ qg, const float* __restrict__ kg,
       float* __restrict__ out)
{
  __shared__ __align__(16) char smem_raw[TILE * LDSTR * 2 * sizeof(short)];
  __shared__ float qn_s[TILE];
  __shared__ float kn_s[TILE];
  short* Qs = (short*)smem_raw;
  short* Ks = Qs + TILE * LDSTR;
  float* Ts = (float*)smem_raw;

  const int t  = threadIdx.x;
  const int bh = blockIdx.z;
  const int ti = blockIdx.y;
  const int tj = blockIdx.x;

  const int row  = t >> 2;
  const int part = t & 3;
  const float* gq = qg + ((size_t)bh * N_SEQ + (size_t)ti * TILE) * D_DIM;
  const float* gk = kg + ((size_t)bh * N_SEQ + (size_t)tj * TILE) * D_DIM;
#pragma unroll
  for (int m = 0; m < 2; ++m) {
    const float* g = (m ? gk : gq) + row * D_DIM + part * 16;
    short* lds     = (m ? Ks : Qs) + row * LDSTR + part * 16;
    float* nrm     = m ? kn_s : qn_s;
    float4 v0 = ((const float4*)g)[0];
    float4 v1 = ((const float4*)g)[1];
    float4 v2 = ((const float4*)g)[2];
    float4 v3 = ((const float4*)g)[3];
    float p = v0.x*v0.x + v0.y*v0.y + v0.z*v0.z + v0.w*v0.w
            + v1.x*v1.x + v1.y*v1.y + v1.z*v1.z + v1.w*v1.w
            + v2.x*v2.x + v2.y*v2.y + v2.z*v2.z + v2.w*v2.w
            + v3.x*v3.x + v3.y*v3.y + v3.z*v3.z + v3.w*v3.w;
    p += __shfl_xor(p, 1);
    p += __shfl_xor(p, 2);
    if (part == 0) nrm[row] = p;
    bf16x8 pk0, pk1;
    pk0[0]=f2bf(v0.x); pk0[1]=f2bf(v0.y); pk0[2]=f2bf(v0.z); pk0[3]=f2bf(v0.w);
    pk0[4]=f2bf(v1.x); pk0[5]=f2bf(v1.y); pk0[6]=f2bf(v1.z); pk0[7]=f2bf(v1.w);
    pk1[0]=f2bf(v2.x); pk1[1]=f2bf(v2.y); pk1[2]=f2bf(v2.z); pk1[3]=f2bf(v2.w);
    pk1[4]=f2bf(v3.x); pk1[5]=f2bf(v3.y); pk1[6]=f2bf(v3.z); pk1[7]=f2bf(v3.w);
    ((bf16x8*)lds)[0] = pk0;
    ((bf16x8*)lds)[1] = pk1;
  }
  __syncthreads();

  const int lane = t & 63;
  const int wv   = t >> 6;
  const int wj   = (wv & 1) * 32;
  const int wi   = (wv >> 1) * 32;
  const int l15  = lane & 15;
  const int quad = lane >> 4;

  const f32x4 zero = {0.0f, 0.0f, 0.0f, 0.0f};
  f32x4 acc[2][2];
#pragma unroll
  for (int a = 0; a < 2; ++a)
#pragma unroll
    for (int b = 0; b < 2; ++b)
      acc[a][b] = zero;

#pragma unroll
  for (int s = 0; s < 2; ++s) {
    const int koff = s * 32 + quad * 8;
    bf16x8 fa[2], fb[2];
#pragma unroll
    for (int mj = 0; mj < 2; ++mj)
      fa[mj] = *(const bf16x8*)&Ks[(wj + mj * 16 + l15) * LDSTR + koff];
#pragma unroll
    for (int ni = 0; ni < 2; ++ni)
      fb[ni] = *(const bf16x8*)&Qs[(wi + ni * 16 + l15) * LDSTR + koff];
#pragma unroll
    for (int mj = 0; mj < 2; ++mj)
#pragma unroll
      for (int ni = 0; ni < 2; ++ni)
        acc[mj][ni] = __builtin_amdgcn_mfma_f32_16x16x32_bf16(
            fa[mj], fb[ni], acc[mj][ni], 0, 0, 0);
  }

  __syncthreads();

#pragma unroll
  for (int mj = 0; mj < 2; ++mj) {
    const int jl = wj + mj * 16 + quad * 4;
    const float4 kn4 = *(const float4*)&kn_s[jl];
#pragma unroll
    for (int ni = 0; ni < 2; ++ni) {
      const int il = wi + ni * 16 + l15;
      const float qns = qn_s[il];
      f32x4 a4 = acc[mj][ni];
      f32x4 res;
      res[0] = hyp_dist_fb(qns, kn4.x, a4[0]);
      res[1] = hyp_dist_fb(qns, kn4.y, a4[1]);
      res[2] = hyp_dist_fb(qns, kn4.z, a4[2]);
      res[3] = hyp_dist_fb(qns, kn4.w, a4[3]);
      *(f32x4*)&Ts[il * TSTR + jl] = res;
    }
  }
  __syncthreads();

  float* outb = out + (size_t)bh * N_SEQ * N_SEQ
                    + (size_t)(ti * TILE) * N_SEQ + tj * TILE;
  const int l  = t & 15;
  const int rq = t >> 4;
#pragma unroll
  for (int p = 0; p < 4; ++p) {
    const int r = p * 16 + rq;
    f32x4 v = *(const f32x4*)&Ts[r * TSTR + 4 * l];
    __builtin_nontemporal_store(v, (f32x4*)(outb + (size_t)r * N_SEQ + 4 * l));
  }
}

extern "C" void kernel_launch(void* const* d_in, const int* in_sizes, int n_in,
                              void* d_out, int out_size, void* d_ws, size_t ws_size,
                              hipStream_t stream) {
  const float* q = (const float*)d_in[0];
  const float* k = (const float*)d_in[1];
  float* out = (float*)d_out;

  if (ws_size >= WS_NEED && d_ws != nullptr) {
    short* qbf  = (short*)d_ws;
    short* kbf  = qbf + 2097152;
    float4* qrow = (float4*)((char*)d_ws + 8388608);
    float4* krow = qrow + NROWS;
    prep_kernel<<<dim3(2048, 1, 1), 256, 0, stream>>>(q, k, qbf, kbf, qrow, krow);
    hyp_main<<<dim3(16384, 1, 1), 256, 0, stream>>>(qbf, kbf, qrow, krow, out);
  } else {
    dim3 grid(N_SEQ / TILE, N_SEQ / TILE, BH_CNT);  // (32,32,16)
    hyp_fb<<<grid, 256, 0, stream>>>(q, k, out);
  }
}